// Round 5
// baseline (321.872 us; speedup 1.0000x reference)
//
#include <hip/hip_runtime.h>
#include <math.h>

#define NB    15
#define BWID  129
#define HOP   64
#define NFREQ 1025
#define EMB   128
#define MLP   512
#define OUTC  516
#define O2    1032
#define BATCH 2
#define TLEN  2048
#define REIM  2
#define CCH   2
#define RTOT  (BATCH*TLEN*NB)

typedef _Float16 half8 __attribute__((ext_vector_type(8)));
typedef _Float16 half4 __attribute__((ext_vector_type(4)));
typedef float    floatx4 __attribute__((ext_vector_type(4)));

#define GLOAD_LDS(gsrc, ldst) \
  __builtin_amdgcn_global_load_lds((const __attribute__((address_space(1))) unsigned int*)(gsrc), \
                                   (__attribute__((address_space(3))) unsigned int*)(ldst), 16, 0, 0)

// ------------- LayerNorm: 32 lanes per row (float4 = 16B/lane), f16 out -------------
__global__ __launch_bounds__(256) void ln_kernel(const float* __restrict__ q,
                                                 const float* __restrict__ gamma,
                                                 const float* __restrict__ beta,
                                                 _Float16* __restrict__ qn)
{
    int row = blockIdx.x * 8 + (threadIdx.x >> 5);
    int l32 = threadIdx.x & 31;
    int n   = (row / TLEN) % NB;

    float4 v = ((const float4*)(q + (size_t)row * EMB))[l32];
    float s  = v.x + v.y + v.z + v.w;
    float s2 = v.x * v.x + v.y * v.y + v.z * v.z + v.w * v.w;
    #pragma unroll
    for (int off = 1; off < 32; off <<= 1) {   // stays within the 32-lane row group
        s  += __shfl_xor(s,  off);
        s2 += __shfl_xor(s2, off);
    }
    float mu   = s * (1.0f / EMB);
    float var  = s2 * (1.0f / EMB) - mu * mu;
    float rstd = rsqrtf(var + 1e-5f);

    float4 g4 = ((const float4*)(gamma + n * EMB))[l32];
    float4 b4 = ((const float4*)(beta  + n * EMB))[l32];
    half4 o;
    o[0] = (_Float16)((v.x - mu) * rstd * g4.x + b4.x);
    o[1] = (_Float16)((v.y - mu) * rstd * g4.y + b4.y);
    o[2] = (_Float16)((v.z - mu) * rstd * g4.z + b4.z);
    o[3] = (_Float16)((v.w - mu) * rstd * g4.w + b4.w);
    ((half4*)(qn + (size_t)row * EMB))[l32] = o;
}

// ------- fused transpose + f32->f16 for W1 and W2 (one launch, 1-D grid) -------
__global__ __launch_bounds__(256) void transpose_cvt_all(const float* __restrict__ W1,
                                                         const float* __restrict__ W2,
                                                         _Float16* __restrict__ W1T,
                                                         _Float16* __restrict__ W2T)
{
    __shared__ float tile[32][33];
    int bid = blockIdx.x;
    const float* src; _Float16* dst; int R, C, bx, by;
    if (bid < 960) {                       // W1: 15 bands x (16 x 4) tiles
        int band = bid >> 6; int t = bid & 63; bx = t & 15; by = t >> 4;
        R = EMB; C = MLP;
        src = W1 + (size_t)band * R * C; dst = W1T + (size_t)band * R * C;
    } else {                               // W2: 15 bands x (33 x 16) tiles
        int b2 = bid - 960;
        int band = b2 / 528; int t = b2 % 528; bx = t % 33; by = t / 33;
        R = MLP; C = O2;
        src = W2 + (size_t)band * R * C; dst = W2T + (size_t)band * R * C;
    }
    int tx = threadIdx.x & 31, ty = threadIdx.x >> 5;
    int c0 = bx * 32, r0 = by * 32;
    int c = c0 + tx;
    if (c < C) {
        #pragma unroll
        for (int i = 0; i < 4; ++i)
            tile[ty + i * 8][tx] = src[(size_t)(r0 + ty + i * 8) * C + c];
    }
    __syncthreads();
    int cl = threadIdx.x >> 3, rq = (threadIdx.x & 7) * 4;
    int cw = c0 + cl;
    if (cw < C) {
        half4 v;
        #pragma unroll
        for (int j = 0; j < 4; ++j) v[j] = (_Float16)tile[rq + j][cl];
        *(half4*)(dst + (size_t)cw * R + r0 + rq) = v;
    }
}

// ---------------- GEMM1 (MFMA f16): qn(4096x128) @ W1T^T -> tanh -> h f16 ----------------
__global__ __launch_bounds__(256) void gemm1_mfma(const _Float16* __restrict__ qn,
                                                  const _Float16* __restrict__ W1T,
                                                  const float* __restrict__ b1,
                                                  _Float16* __restrict__ h)
{
    __shared__ _Float16 sA[128 * 64];
    __shared__ _Float16 sB[128 * 64];
    const int n   = blockIdx.z;
    const int m0  = blockIdx.y * 128;
    const int n0  = blockIdx.x * 128;
    const int tid = threadIdx.x;
    const int lane = tid & 63;
    const int wave = tid >> 6;
    const int wr = (wave >> 1) * 64;
    const int wc = (wave & 1) * 64;
    const int b = m0 >> 11, t0 = m0 & (TLEN - 1);

    const _Float16* Ab = qn  + ((size_t)(b * NB + n) * TLEN + t0) * EMB;
    const _Float16* Bb = W1T + ((size_t)n * MLP + n0) * EMB;

    floatx4 acc[4][4] = {};

    const int lrow = lane & 15;
    const int q16  = (lane >> 4) << 4;
    const int swz  = (lane & 7) << 4;

    for (int k0 = 0; k0 < EMB; k0 += 64) {
        #pragma unroll
        for (int i = 0; i < 4; ++i) {
            int g = tid + i * 256;
            int r = g >> 3, kb = g & 7;
            int sk = kb ^ (r & 7);
            GLOAD_LDS(Ab + (size_t)r * EMB + k0 + sk * 8, sA + g * 8);
            GLOAD_LDS(Bb + (size_t)r * EMB + k0 + sk * 8, sB + g * 8);
        }
        __syncthreads();
        #pragma unroll
        for (int kk = 0; kk < 2; ++kk) {
            half8 af[4], bf[4];
            #pragma unroll
            for (int m = 0; m < 4; ++m) {
                int r = wr + m * 16 + lrow;
                af[m] = *(const half8*)((const char*)sA + r * 128 + (((kk << 6) | q16) ^ swz));
            }
            #pragma unroll
            for (int nf = 0; nf < 4; ++nf) {
                int r = wc + nf * 16 + lrow;
                bf[nf] = *(const half8*)((const char*)sB + r * 128 + (((kk << 6) | q16) ^ swz));
            }
            #pragma unroll
            for (int m = 0; m < 4; ++m)
                #pragma unroll
                for (int nf = 0; nf < 4; ++nf)
                    acc[m][nf] = __builtin_amdgcn_mfma_f32_16x16x32_f16(af[m], bf[nf], acc[m][nf], 0, 0, 0);
        }
        __syncthreads();
    }

    const int rq = (lane >> 4) * 4;
    _Float16* hb = h + ((size_t)(b * NB + n) * TLEN + t0) * MLP;
    #pragma unroll
    for (int nf = 0; nf < 4; ++nf) {
        int col = n0 + wc + nf * 16 + lrow;
        float bias = b1[n * MLP + col];
        #pragma unroll
        for (int m = 0; m < 4; ++m) {
            int rbase = wr + m * 16 + rq;
            #pragma unroll
            for (int r = 0; r < 4; ++r) {
                float v = tanhf(acc[m][nf][r] + bias);
                hb[(size_t)(rbase + r) * MLP + col] = (_Float16)v;
            }
        }
    }
}

// ---- GEMM2, T3-minimum 2-phase: 256 rows x (64a+64g), BK=64, double-buffered LDS.
// Per K-tile: issue next tile's 6 global_load_lds FIRST, then 16 ds_read_b128 +
// 32 MFMA on current tile, then ONE __syncthreads (compiler drains vmcnt+lgkm there,
// so the HBM latency of the prefetch hides under the MFMA cluster). ----
__global__ __launch_bounds__(512) void gemm2_mfma(const _Float16* __restrict__ h,
                                                  const _Float16* __restrict__ W2T,
                                                  const float* __restrict__ b2,
                                                  const float* __restrict__ fw,
                                                  _Float16* __restrict__ mws)
{
    __shared__ _Float16 sA[2 * 256 * 64];   // 2 x 32 KB
    __shared__ _Float16 sB[2 * 128 * 64];   // 2 x 16 KB (a rows 0-63, g rows 64-127)

    const int NWG = 9 * 16 * NB;            // 2160, %8==0 -> bijective XCD swizzle
    int flat = blockIdx.x;
    int wg   = (flat & 7) * (NWG / 8) + (flat >> 3);
    int bx   = wg % 9;
    int tmp  = wg / 9;
    int by   = tmp & 15;
    int n    = tmp >> 4;

    const int m0  = by * 256;
    const int n0  = bx * 64;
    const int tid = threadIdx.x;
    const int lane = tid & 63;
    const int wave = tid >> 6;
    const int wm = (wave >> 1) * 64;
    const int wc = (wave & 1) * 32;
    const int b = m0 >> 11, t0 = m0 & (TLEN - 1);

    const _Float16* Ab  = h   + ((size_t)(b * NB + n) * TLEN + t0) * MLP;
    const _Float16* W2n = W2T + (size_t)n * O2 * MLP;

    floatx4 accA[4][2] = {};
    floatx4 accG[4][2] = {};

    const int lrow = lane & 15;
    const int q16  = (lane >> 4) << 4;
    const int swz  = (lane & 7) << 4;

    auto stage = [&](int slot, int k0) {
        #pragma unroll
        for (int i = 0; i < 4; ++i) {
            int g = tid + i * 512;
            int r = g >> 3;
            int sk = (g & 7) ^ (r & 7);
            GLOAD_LDS(Ab + (size_t)r * MLP + k0 + sk * 8, sA + slot * 16384 + g * 8);
        }
        {
            int g = tid, r = g >> 3;
            int sk = (g & 7) ^ (r & 7);
            int ra = n0 + r;        if (ra > OUTC - 1) ra = OUTC - 1;
            int rg = OUTC + n0 + r; if (rg > O2 - 1)   rg = O2 - 1;
            GLOAD_LDS(W2n + (size_t)ra * MLP + k0 + sk * 8, sB + slot * 8192 + g * 8);
            GLOAD_LDS(W2n + (size_t)rg * MLP + k0 + sk * 8, sB + slot * 8192 + 4096 + g * 8);
        }
    };

    stage(0, 0);
    __syncthreads();                        // tile 0 ready (implicit vmcnt(0) drain)

    for (int kt = 0; kt < 8; ++kt) {
        const int cur = kt & 1;
        if (kt < 7) stage(cur ^ 1, (kt + 1) * 64);   // prefetch BEFORE compute
        const _Float16* sAc = sA + cur * 16384;
        const _Float16* sBc = sB + cur * 8192;
        #pragma unroll
        for (int kk = 0; kk < 2; ++kk) {
            half8 af[4], ba[2], bg[2];
            const int koff = (kk << 6) | q16;
            #pragma unroll
            for (int m = 0; m < 4; ++m)
                af[m] = *(const half8*)((const char*)sAc + (wm + m * 16 + lrow) * 128 + (koff ^ swz));
            #pragma unroll
            for (int nf = 0; nf < 2; ++nf) {
                ba[nf] = *(const half8*)((const char*)sBc + (wc + nf * 16 + lrow) * 128 + (koff ^ swz));
                bg[nf] = *(const half8*)((const char*)sBc + 8192 + (wc + nf * 16 + lrow) * 128 + (koff ^ swz));
            }
            __builtin_amdgcn_s_setprio(1);
            #pragma unroll
            for (int m = 0; m < 4; ++m)
                #pragma unroll
                for (int nf = 0; nf < 2; ++nf) {
                    accA[m][nf] = __builtin_amdgcn_mfma_f32_16x16x32_f16(af[m], ba[nf], accA[m][nf], 0, 0, 0);
                    accG[m][nf] = __builtin_amdgcn_mfma_f32_16x16x32_f16(af[m], bg[nf], accG[m][nf], 0, 0, 0);
                }
            __builtin_amdgcn_s_setprio(0);
        }
        __syncthreads();                    // one barrier per K-tile: next tile ready
    }

    const int rq = (lane >> 4) * 4;
    const float* b2n = b2 + n * O2;
    #pragma unroll
    for (int nf = 0; nf < 2; ++nf) {
        int c = n0 + wc + nf * 16 + lrow;
        bool valid = c < OUTC;
        int cl = valid ? c : OUTC - 1;
        float biasA = b2n[cl];
        float biasG = b2n[OUTC + cl];
        int rem = cl % 258;
        float w = fw[n * BWID + (rem >> 1)];
        _Float16* mb = mws + ((size_t)((b * NB + n) * OUTC + cl)) * TLEN + t0;
        #pragma unroll
        for (int m = 0; m < 4; ++m) {
            int tb = wm + m * 16 + rq;
            half4 vals;
            #pragma unroll
            for (int r = 0; r < 4; ++r) {
                float a = accA[m][nf][r] + biasA;
                float g = accG[m][nf][r] + biasG;
                vals[r] = (_Float16)(a * w / (1.0f + expf(-g)));
            }
            if (valid) *(half4*)(mb + tb) = vals;
        }
    }
}

// ---------------- gather: vectorized, 8 t-values per thread ----------------
__global__ __launch_bounds__(256) void gather_masks(const _Float16* __restrict__ mws,
                                                    float* __restrict__ out)
{
    const int f  = blockIdx.x;
    const int bc = blockIdx.y;
    const int b  = bc >> 1, cc = bc & 1;
    int nlo = (f >= 129) ? ((f - 65) >> 6) : 0;
    int nhi = f >> 6; if (nhi > 14) nhi = 14;
    const int t0 = threadIdx.x * 8;

    float a[8] = {0,0,0,0,0,0,0,0};
    float g[8] = {0,0,0,0,0,0,0,0};
    for (int nn = nlo; nn <= nhi; ++nn) {
        int bw = f - (nn << 6);
        int cbase = cc * 258 + (bw << 1);
        const _Float16* p = mws + ((size_t)((b * NB + nn) * OUTC + cbase)) * TLEN + t0;
        half8 va = *(const half8*)p;
        half8 vg = *(const half8*)(p + TLEN);
        #pragma unroll
        for (int j = 0; j < 8; ++j) { a[j] += (float)va[j]; g[j] += (float)vg[j]; }
    }
    float* ob = out + (((size_t)bc * NFREQ + f) * TLEN + t0) * REIM;
    #pragma unroll
    for (int j = 0; j < 4; ++j) {
        float4 v = make_float4(a[2*j], g[2*j], a[2*j+1], g[2*j+1]);
        *(float4*)(ob + j * 4) = v;
    }
}

extern "C" void kernel_launch(void* const* d_in, const int* in_sizes, int n_in,
                              void* d_out, int out_size, void* d_ws, size_t ws_size,
                              hipStream_t stream) {
    const float* q     = (const float*)d_in[0];
    const float* gamma = (const float*)d_in[1];
    const float* beta  = (const float*)d_in[2];
    const float* W1    = (const float*)d_in[3];
    const float* b1    = (const float*)d_in[4];
    const float* W2    = (const float*)d_in[5];
    const float* b2    = (const float*)d_in[6];
    const float* fw    = (const float*)d_in[7];

    _Float16* hws  = (_Float16*)d_ws;
    _Float16* mws  = hws + (size_t)RTOT * MLP;
    _Float16* qnws = mws + (size_t)BATCH * NB * OUTC * TLEN;
    _Float16* W1T  = qnws + (size_t)RTOT * EMB;
    _Float16* W2T  = W1T + (size_t)NB * EMB * MLP;

    ln_kernel<<<RTOT / 8, 256, 0, stream>>>(q, gamma, beta, qnws);
    transpose_cvt_all<<<960 + 528 * NB, 256, 0, stream>>>(W1, W2, W1T, W2T);
    gemm1_mfma<<<dim3(4, 32, NB), 256, 0, stream>>>(qnws, W1T, b1, hws);
    gemm2_mfma<<<9 * 16 * NB, 512, 0, stream>>>(hws, W2T, b2, fw, mws);
    gather_masks<<<dim3(NFREQ, BATCH * CCH), 256, 0, stream>>>(mws, (float*)d_out);
}

// Round 7
// 268.282 us; speedup vs baseline: 1.1998x; 1.1998x over previous
//
#include <hip/hip_runtime.h>
#include <math.h>

#define NB    15
#define BWID  129
#define HOP   64
#define NFREQ 1025
#define EMB   128
#define MLP   512
#define OUTC  516
#define O2    1032
#define BATCH 2
#define TLEN  2048
#define REIM  2
#define CCH   2
#define RTOT  (BATCH*TLEN*NB)

typedef _Float16 half8 __attribute__((ext_vector_type(8)));
typedef _Float16 half4 __attribute__((ext_vector_type(4)));
typedef float    floatx4 __attribute__((ext_vector_type(4)));

#define GLOAD_LDS(gsrc, ldst) \
  __builtin_amdgcn_global_load_lds((const __attribute__((address_space(1))) unsigned int*)(gsrc), \
                                   (__attribute__((address_space(3))) unsigned int*)(ldst), 16, 0, 0)

__device__ __forceinline__ float fast_tanh(float x) {
    x = fminf(12.0f, fmaxf(-12.0f, x));
    float e = __expf(2.0f * x);
    return (e - 1.0f) * __builtin_amdgcn_rcpf(e + 1.0f);
}
__device__ __forceinline__ float fast_sigmoid(float g) {
    return __builtin_amdgcn_rcpf(1.0f + __expf(-g));
}

// ------------- LayerNorm: 32 lanes per row (float4 = 16B/lane), f16 out -------------
__global__ __launch_bounds__(256) void ln_kernel(const float* __restrict__ q,
                                                 const float* __restrict__ gamma,
                                                 const float* __restrict__ beta,
                                                 _Float16* __restrict__ qn)
{
    int row = blockIdx.x * 8 + (threadIdx.x >> 5);
    int l32 = threadIdx.x & 31;
    int n   = (row / TLEN) % NB;

    float4 v = ((const float4*)(q + (size_t)row * EMB))[l32];
    float s  = v.x + v.y + v.z + v.w;
    float s2 = v.x * v.x + v.y * v.y + v.z * v.z + v.w * v.w;
    #pragma unroll
    for (int off = 1; off < 32; off <<= 1) {
        s  += __shfl_xor(s,  off);
        s2 += __shfl_xor(s2, off);
    }
    float mu   = s * (1.0f / EMB);
    float var  = s2 * (1.0f / EMB) - mu * mu;
    float rstd = rsqrtf(var + 1e-5f);

    float4 g4 = ((const float4*)(gamma + n * EMB))[l32];
    float4 b4 = ((const float4*)(beta  + n * EMB))[l32];
    half4 o;
    o[0] = (_Float16)((v.x - mu) * rstd * g4.x + b4.x);
    o[1] = (_Float16)((v.y - mu) * rstd * g4.y + b4.y);
    o[2] = (_Float16)((v.z - mu) * rstd * g4.z + b4.z);
    o[3] = (_Float16)((v.w - mu) * rstd * g4.w + b4.w);
    ((half4*)(qn + (size_t)row * EMB))[l32] = o;
}

// ------- fused transpose + f32->f16 for W1 and W2 (one launch, 1-D grid) -------
__global__ __launch_bounds__(256) void transpose_cvt_all(const float* __restrict__ W1,
                                                         const float* __restrict__ W2,
                                                         _Float16* __restrict__ W1T,
                                                         _Float16* __restrict__ W2T)
{
    __shared__ float tile[32][33];
    int bid = blockIdx.x;
    const float* src; _Float16* dst; int R, C, bx, by;
    if (bid < 960) {                       // W1: 15 bands x (16 x 4) tiles
        int band = bid >> 6; int t = bid & 63; bx = t & 15; by = t >> 4;
        R = EMB; C = MLP;
        src = W1 + (size_t)band * R * C; dst = W1T + (size_t)band * R * C;
    } else {                               // W2: 15 bands x (33 x 16) tiles
        int b2 = bid - 960;
        int band = b2 / 528; int t = b2 % 528; bx = t % 33; by = t / 33;
        R = MLP; C = O2;
        src = W2 + (size_t)band * R * C; dst = W2T + (size_t)band * R * C;
    }
    int tx = threadIdx.x & 31, ty = threadIdx.x >> 5;
    int c0 = bx * 32, r0 = by * 32;
    int c = c0 + tx;
    if (c < C) {
        #pragma unroll
        for (int i = 0; i < 4; ++i)
            tile[ty + i * 8][tx] = src[(size_t)(r0 + ty + i * 8) * C + c];
    }
    __syncthreads();
    int cl = threadIdx.x >> 3, rq = (threadIdx.x & 7) * 4;
    int cw = c0 + cl;
    if (cw < C) {
        half4 v;
        #pragma unroll
        for (int j = 0; j < 4; ++j) v[j] = (_Float16)tile[rq + j][cl];
        *(half4*)(dst + (size_t)cw * R + r0 + rq) = v;
    }
}

// ---- GEMM1 (MFMA f16), single K-pass: 128x128 tile, BK=EMB=128, 64 KB LDS.
// One stage (16 gload_lds/thread) -> one barrier drain -> 64 MFMA/wave -> epilogue. ----
__global__ __launch_bounds__(256) void gemm1_mfma(const _Float16* __restrict__ qn,
                                                  const _Float16* __restrict__ W1T,
                                                  const float* __restrict__ b1,
                                                  _Float16* __restrict__ h)
{
    __shared__ _Float16 sA[128 * 128];
    __shared__ _Float16 sB[128 * 128];
    const int n   = blockIdx.z;
    const int m0  = blockIdx.y * 128;
    const int n0  = blockIdx.x * 128;
    const int tid = threadIdx.x;
    const int lane = tid & 63;
    const int wave = tid >> 6;
    const int wr = (wave >> 1) * 64;
    const int wc = (wave & 1) * 64;
    const int b = m0 >> 11, t0 = m0 & (TLEN - 1);

    const _Float16* Ab = qn  + ((size_t)(b * NB + n) * TLEN + t0) * EMB;
    const _Float16* Bb = W1T + ((size_t)n * MLP + n0) * EMB;

    // stage both 128x128 f16 tiles (16 chunks of 16B per row; XOR-swizzled source)
    #pragma unroll
    for (int i = 0; i < 8; ++i) {
        int g = tid + i * 256;
        int r = g >> 4, kb = g & 15;
        int sk = kb ^ (r & 7);
        GLOAD_LDS(Ab + (size_t)r * EMB + sk * 8, sA + g * 8);
        GLOAD_LDS(Bb + (size_t)r * EMB + sk * 8, sB + g * 8);
    }
    __syncthreads();

    floatx4 acc[4][4] = {};
    const int lrow = lane & 15;
    const int qk   = lane >> 4;          // k-quarter within K=32
    const int swz  = lrow & 7;

    #pragma unroll
    for (int kk = 0; kk < 4; ++kk) {
        half8 af[4], bf[4];
        const int chunk = kk * 4 + qk;
        #pragma unroll
        for (int m = 0; m < 4; ++m) {
            int r = wr + m * 16 + lrow;
            af[m] = *(const half8*)((const char*)sA + r * 256 + ((chunk ^ swz) << 4));
        }
        #pragma unroll
        for (int nf = 0; nf < 4; ++nf) {
            int r = wc + nf * 16 + lrow;
            bf[nf] = *(const half8*)((const char*)sB + r * 256 + ((chunk ^ swz) << 4));
        }
        #pragma unroll
        for (int m = 0; m < 4; ++m)
            #pragma unroll
            for (int nf = 0; nf < 4; ++nf)
                acc[m][nf] = __builtin_amdgcn_mfma_f32_16x16x32_f16(af[m], bf[nf], acc[m][nf], 0, 0, 0);
    }

    const int rq = (lane >> 4) * 4;
    _Float16* hb = h + ((size_t)(b * NB + n) * TLEN + t0) * MLP;
    #pragma unroll
    for (int nf = 0; nf < 4; ++nf) {
        int col = n0 + wc + nf * 16 + lrow;
        float bias = b1[n * MLP + col];
        #pragma unroll
        for (int m = 0; m < 4; ++m) {
            int rbase = wr + m * 16 + rq;
            #pragma unroll
            for (int r = 0; r < 4; ++r) {
                float v = fast_tanh(acc[m][nf][r] + bias);
                hb[(size_t)(rbase + r) * MLP + col] = (_Float16)v;
            }
        }
    }
}

// ---- GEMM2 (R3-proven structure): 256 rows x (64a+64g), BK=64, single-buffer 48 KB,
// stage -> sync -> 2x(ds_read + 16 MFMA) -> sync, XCD-swizzled 1-D grid ----
__global__ __launch_bounds__(512) void gemm2_mfma(const _Float16* __restrict__ h,
                                                  const _Float16* __restrict__ W2T,
                                                  const float* __restrict__ b2,
                                                  const float* __restrict__ fw,
                                                  _Float16* __restrict__ mws)
{
    __shared__ _Float16 sA[256 * 64];
    __shared__ _Float16 sBa[64 * 64];
    __shared__ _Float16 sBg[64 * 64];

    const int NWG = 9 * 16 * NB;            // 2160, %8==0 -> bijective XCD swizzle
    int flat = blockIdx.x;
    int wg   = (flat & 7) * (NWG / 8) + (flat >> 3);
    int bx   = wg % 9;
    int tmp  = wg / 9;
    int by   = tmp & 15;
    int n    = tmp >> 4;

    const int m0  = by * 256;
    const int n0  = bx * 64;
    const int tid = threadIdx.x;
    const int lane = tid & 63;
    const int wave = tid >> 6;
    const int wm = (wave >> 1) * 64;
    const int wc = (wave & 1) * 32;
    const int b = m0 >> 11, t0 = m0 & (TLEN - 1);

    const _Float16* Ab  = h   + ((size_t)(b * NB + n) * TLEN + t0) * MLP;
    const _Float16* W2n = W2T + (size_t)n * O2 * MLP;

    floatx4 accA[4][2] = {};
    floatx4 accG[4][2] = {};

    const int lrow = lane & 15;
    const int q16  = (lane >> 4) << 4;
    const int swz  = (lane & 7) << 4;

    for (int k0 = 0; k0 < MLP; k0 += 64) {
        #pragma unroll
        for (int i = 0; i < 4; ++i) {
            int g = tid + i * 512;
            int r = g >> 3, kb = g & 7;
            int sk = kb ^ (r & 7);
            GLOAD_LDS(Ab + (size_t)r * MLP + k0 + sk * 8, sA + g * 8);
        }
        {
            int g = tid, r = g >> 3;
            int sk = (g & 7) ^ (r & 7);
            int ra = n0 + r;        if (ra > OUTC - 1) ra = OUTC - 1;
            int rg = OUTC + n0 + r; if (rg > O2 - 1)   rg = O2 - 1;
            GLOAD_LDS(W2n + (size_t)ra * MLP + k0 + sk * 8, sBa + g * 8);
            GLOAD_LDS(W2n + (size_t)rg * MLP + k0 + sk * 8, sBg + g * 8);
        }
        __syncthreads();
        #pragma unroll
        for (int kk = 0; kk < 2; ++kk) {
            half8 af[4], ba[2], bg[2];
            const int koff = (kk << 6) | q16;
            #pragma unroll
            for (int m = 0; m < 4; ++m)
                af[m] = *(const half8*)((const char*)sA + (wm + m * 16 + lrow) * 128 + (koff ^ swz));
            #pragma unroll
            for (int nf = 0; nf < 2; ++nf) {
                ba[nf] = *(const half8*)((const char*)sBa + (wc + nf * 16 + lrow) * 128 + (koff ^ swz));
                bg[nf] = *(const half8*)((const char*)sBg + (wc + nf * 16 + lrow) * 128 + (koff ^ swz));
            }
            #pragma unroll
            for (int m = 0; m < 4; ++m)
                #pragma unroll
                for (int nf = 0; nf < 2; ++nf) {
                    accA[m][nf] = __builtin_amdgcn_mfma_f32_16x16x32_f16(af[m], ba[nf], accA[m][nf], 0, 0, 0);
                    accG[m][nf] = __builtin_amdgcn_mfma_f32_16x16x32_f16(af[m], bg[nf], accG[m][nf], 0, 0, 0);
                }
        }
        __syncthreads();
    }

    const int rq = (lane >> 4) * 4;
    const float* b2n = b2 + n * O2;
    #pragma unroll
    for (int nf = 0; nf < 2; ++nf) {
        int c = n0 + wc + nf * 16 + lrow;
        bool valid = c < OUTC;
        int cl = valid ? c : OUTC - 1;
        float biasA = b2n[cl];
        float biasG = b2n[OUTC + cl];
        int rem = cl % 258;
        float w = fw[n * BWID + (rem >> 1)];
        _Float16* mb = mws + ((size_t)((b * NB + n) * OUTC + cl)) * TLEN + t0;
        #pragma unroll
        for (int m = 0; m < 4; ++m) {
            int tb = wm + m * 16 + rq;
            half4 vals;
            #pragma unroll
            for (int r = 0; r < 4; ++r) {
                float a = accA[m][nf][r] + biasA;
                float g = accG[m][nf][r] + biasG;
                vals[r] = (_Float16)(a * w * fast_sigmoid(g));
            }
            if (valid) *(half4*)(mb + tb) = vals;
        }
    }
}

// ---------------- gather: vectorized, 8 t-values per thread ----------------
__global__ __launch_bounds__(256) void gather_masks(const _Float16* __restrict__ mws,
                                                    float* __restrict__ out)
{
    const int f  = blockIdx.x;
    const int bc = blockIdx.y;
    const int b  = bc >> 1, cc = bc & 1;
    int nlo = (f >= 129) ? ((f - 65) >> 6) : 0;
    int nhi = f >> 6; if (nhi > 14) nhi = 14;
    const int t0 = threadIdx.x * 8;

    float a[8] = {0,0,0,0,0,0,0,0};
    float g[8] = {0,0,0,0,0,0,0,0};
    for (int nn = nlo; nn <= nhi; ++nn) {
        int bw = f - (nn << 6);
        int cbase = cc * 258 + (bw << 1);
        const _Float16* p = mws + ((size_t)((b * NB + nn) * OUTC + cbase)) * TLEN + t0;
        half8 va = *(const half8*)p;
        half8 vg = *(const half8*)(p + TLEN);
        #pragma unroll
        for (int j = 0; j < 8; ++j) { a[j] += (float)va[j]; g[j] += (float)vg[j]; }
    }
    float* ob = out + (((size_t)bc * NFREQ + f) * TLEN + t0) * REIM;
    #pragma unroll
    for (int j = 0; j < 4; ++j) {
        float4 v = make_float4(a[2*j], g[2*j], a[2*j+1], g[2*j+1]);
        *(float4*)(ob + j * 4) = v;
    }
}

extern "C" void kernel_launch(void* const* d_in, const int* in_sizes, int n_in,
                              void* d_out, int out_size, void* d_ws, size_t ws_size,
                              hipStream_t stream) {
    const float* q     = (const float*)d_in[0];
    const float* gamma = (const float*)d_in[1];
    const float* beta  = (const float*)d_in[2];
    const float* W1    = (const float*)d_in[3];
    const float* b1    = (const float*)d_in[4];
    const float* W2    = (const float*)d_in[5];
    const float* b2    = (const float*)d_in[6];
    const float* fw    = (const float*)d_in[7];

    _Float16* hws  = (_Float16*)d_ws;
    _Float16* mws  = hws + (size_t)RTOT * MLP;
    _Float16* qnws = mws + (size_t)BATCH * NB * OUTC * TLEN;
    _Float16* W1T  = qnws + (size_t)RTOT * EMB;
    _Float16* W2T  = W1T + (size_t)NB * EMB * MLP;

    ln_kernel<<<RTOT / 8, 256, 0, stream>>>(q, gamma, beta, qnws);
    transpose_cvt_all<<<960 + 528 * NB, 256, 0, stream>>>(W1, W2, W1T, W2T);
    gemm1_mfma<<<dim3(4, 32, NB), 256, 0, stream>>>(qnws, W1T, b1, hws);
    gemm2_mfma<<<9 * 16 * NB, 512, 0, stream>>>(hws, W2T, b2, fw, mws);
    gather_masks<<<dim3(NFREQ, BATCH * CCH), 256, 0, stream>>>(mws, (float*)d_out);
}

// Round 8
// 255.515 us; speedup vs baseline: 1.2597x; 1.0500x over previous
//
#include <hip/hip_runtime.h>
#include <math.h>

#define NB    15
#define BWID  129
#define HOP   64
#define NFREQ 1025
#define EMB   128
#define MLP   512
#define OUTC  516
#define O2    1032
#define BATCH 2
#define TLEN  2048
#define REIM  2
#define CCH   2
#define RTOT  (BATCH*TLEN*NB)

typedef _Float16 half8 __attribute__((ext_vector_type(8)));
typedef _Float16 half4 __attribute__((ext_vector_type(4)));
typedef float    floatx4 __attribute__((ext_vector_type(4)));

#define GLOAD_LDS(gsrc, ldst) \
  __builtin_amdgcn_global_load_lds((const __attribute__((address_space(1))) unsigned int*)(gsrc), \
                                   (__attribute__((address_space(3))) unsigned int*)(ldst), 16, 0, 0)

__device__ __forceinline__ float fast_tanh(float x) {
    x = fminf(12.0f, fmaxf(-12.0f, x));
    float e = __expf(2.0f * x);
    return (e - 1.0f) * __builtin_amdgcn_rcpf(e + 1.0f);
}
__device__ __forceinline__ float fast_sigmoid(float g) {
    return __builtin_amdgcn_rcpf(1.0f + __expf(-g));
}

// ------------- LayerNorm: 32 lanes per row (float4 = 16B/lane), f16 out -------------
__global__ __launch_bounds__(256) void ln_kernel(const float* __restrict__ q,
                                                 const float* __restrict__ gamma,
                                                 const float* __restrict__ beta,
                                                 _Float16* __restrict__ qn)
{
    int row = blockIdx.x * 8 + (threadIdx.x >> 5);
    int l32 = threadIdx.x & 31;
    int n   = (row / TLEN) % NB;

    float4 v = ((const float4*)(q + (size_t)row * EMB))[l32];
    float s  = v.x + v.y + v.z + v.w;
    float s2 = v.x * v.x + v.y * v.y + v.z * v.z + v.w * v.w;
    #pragma unroll
    for (int off = 1; off < 32; off <<= 1) {
        s  += __shfl_xor(s,  off);
        s2 += __shfl_xor(s2, off);
    }
    float mu   = s * (1.0f / EMB);
    float var  = s2 * (1.0f / EMB) - mu * mu;
    float rstd = rsqrtf(var + 1e-5f);

    float4 g4 = ((const float4*)(gamma + n * EMB))[l32];
    float4 b4 = ((const float4*)(beta  + n * EMB))[l32];
    half4 o;
    o[0] = (_Float16)((v.x - mu) * rstd * g4.x + b4.x);
    o[1] = (_Float16)((v.y - mu) * rstd * g4.y + b4.y);
    o[2] = (_Float16)((v.z - mu) * rstd * g4.z + b4.z);
    o[3] = (_Float16)((v.w - mu) * rstd * g4.w + b4.w);
    ((half4*)(qn + (size_t)row * EMB))[l32] = o;
}

// ------- fused transpose + f32->f16, 64x64 tiles: W1 (240 blocks) + W2 (2040) -------
__global__ __launch_bounds__(256) void transpose_cvt_all(const float* __restrict__ W1,
                                                         const float* __restrict__ W2,
                                                         _Float16* __restrict__ W1T,
                                                         _Float16* __restrict__ W2T)
{
    __shared__ float tile[64][65];
    int bid = blockIdx.x;
    const float* src; _Float16* dst; int R, C, bx, by;
    if (bid < 240) {                       // W1: 15 bands x (8c x 2r) tiles of 64x64
        int band = bid >> 4; int t = bid & 15; bx = t & 7; by = t >> 3;
        R = EMB; C = MLP;
        src = W1 + (size_t)band * R * C; dst = W1T + (size_t)band * R * C;
    } else {                               // W2: 15 bands x (17c x 8r) tiles
        int b2 = bid - 240;
        int band = b2 / 136; int t = b2 % 136; bx = t % 17; by = t / 17;
        R = MLP; C = O2;
        src = W2 + (size_t)band * R * C; dst = W2T + (size_t)band * R * C;
    }
    int tx = threadIdx.x & 63, ty = threadIdx.x >> 6;   // ty 0..3
    int c0 = bx * 64, r0 = by * 64;
    int c = c0 + tx;
    if (c < C) {
        #pragma unroll
        for (int i = 0; i < 16; ++i)
            tile[ty + i * 4][tx] = src[(size_t)(r0 + ty + i * 4) * C + c];
    }
    __syncthreads();
    int cl = threadIdx.x >> 3;             // 0..31
    int rq = (threadIdx.x & 7) * 8;        // 0..56
    #pragma unroll
    for (int half = 0; half < 2; ++half) {
        int cc = cl + half * 32;
        int cw = c0 + cc;
        if (cw < C) {
            half8 v;
            #pragma unroll
            for (int j = 0; j < 8; ++j) v[j] = (_Float16)tile[rq + j][cc];
            *(half8*)(dst + (size_t)cw * R + r0 + rq) = v;
        }
    }
}

// ---- GEMM1 (MFMA f16), single K-pass: 128x128 tile, BK=EMB=128, 64 KB LDS,
// 512 thr / 8 waves (2M x 4N), 1-D grid with bx-fastest XCD-chunk swizzle so the
// 4 bx-siblings sharing one A-tile land on the same XCD's L2. ----
__global__ __launch_bounds__(512) void gemm1_mfma(const _Float16* __restrict__ qn,
                                                  const _Float16* __restrict__ W1T,
                                                  const float* __restrict__ b1,
                                                  _Float16* __restrict__ h)
{
    __shared__ _Float16 sA[128 * 128];
    __shared__ _Float16 sB[128 * 128];

    const int NWG = 4 * 32 * NB;           // 1920, %8==0 -> bijective
    int flat = blockIdx.x;
    int wg   = (flat & 7) * (NWG / 8) + (flat >> 3);
    const int bx = wg & 3;
    const int by = (wg >> 2) & 31;
    const int n  = wg >> 7;

    const int m0  = by * 128;
    const int n0  = bx * 128;
    const int tid = threadIdx.x;
    const int lane = tid & 63;
    const int wave = tid >> 6;
    const int wm = (wave >> 2) * 64;       // 0,64
    const int wc = (wave & 3) * 32;        // 0,32,64,96
    const int b = m0 >> 11, t0 = m0 & (TLEN - 1);

    const _Float16* Ab = qn  + ((size_t)(b * NB + n) * TLEN + t0) * EMB;
    const _Float16* Bb = W1T + ((size_t)n * MLP + n0) * EMB;

    // stage both 128x128 f16 tiles (4 chunks of 16B per thread per tile)
    #pragma unroll
    for (int i = 0; i < 4; ++i) {
        int g = tid + i * 512;
        int r = g >> 4, kb = g & 15;
        int sk = kb ^ (r & 7);
        GLOAD_LDS(Ab + (size_t)r * EMB + sk * 8, sA + g * 8);
        GLOAD_LDS(Bb + (size_t)r * EMB + sk * 8, sB + g * 8);
    }
    __syncthreads();

    floatx4 acc[4][2] = {};
    const int lrow = lane & 15;
    const int qk   = lane >> 4;            // k-quarter within K=32
    const int swz  = lrow & 7;

    #pragma unroll
    for (int kk = 0; kk < 4; ++kk) {
        half8 af[4], bf[2];
        const int chunk = kk * 4 + qk;
        #pragma unroll
        for (int m = 0; m < 4; ++m) {
            int r = wm + m * 16 + lrow;
            af[m] = *(const half8*)((const char*)sA + r * 256 + ((chunk ^ swz) << 4));
        }
        #pragma unroll
        for (int nf = 0; nf < 2; ++nf) {
            int r = wc + nf * 16 + lrow;
            bf[nf] = *(const half8*)((const char*)sB + r * 256 + ((chunk ^ swz) << 4));
        }
        #pragma unroll
        for (int m = 0; m < 4; ++m)
            #pragma unroll
            for (int nf = 0; nf < 2; ++nf)
                acc[m][nf] = __builtin_amdgcn_mfma_f32_16x16x32_f16(af[m], bf[nf], acc[m][nf], 0, 0, 0);
    }

    const int rq = (lane >> 4) * 4;
    _Float16* hb = h + ((size_t)(b * NB + n) * TLEN + t0) * MLP;
    #pragma unroll
    for (int nf = 0; nf < 2; ++nf) {
        int col = n0 + wc + nf * 16 + lrow;
        float bias = b1[n * MLP + col];
        #pragma unroll
        for (int m = 0; m < 4; ++m) {
            int rbase = wm + m * 16 + rq;
            #pragma unroll
            for (int r = 0; r < 4; ++r) {
                float v = fast_tanh(acc[m][nf][r] + bias);
                hb[(size_t)(rbase + r) * MLP + col] = (_Float16)v;
            }
        }
    }
}

// ---- GEMM2 (R7-proven, UNCHANGED): 256 rows x (64a+64g), BK=64, 48 KB single-buffer ----
__global__ __launch_bounds__(512) void gemm2_mfma(const _Float16* __restrict__ h,
                                                  const _Float16* __restrict__ W2T,
                                                  const float* __restrict__ b2,
                                                  const float* __restrict__ fw,
                                                  _Float16* __restrict__ mws)
{
    __shared__ _Float16 sA[256 * 64];
    __shared__ _Float16 sBa[64 * 64];
    __shared__ _Float16 sBg[64 * 64];

    const int NWG = 9 * 16 * NB;            // 2160, %8==0 -> bijective XCD swizzle
    int flat = blockIdx.x;
    int wg   = (flat & 7) * (NWG / 8) + (flat >> 3);
    int bx   = wg % 9;
    int tmp  = wg / 9;
    int by   = tmp & 15;
    int n    = tmp >> 4;

    const int m0  = by * 256;
    const int n0  = bx * 64;
    const int tid = threadIdx.x;
    const int lane = tid & 63;
    const int wave = tid >> 6;
    const int wm = (wave >> 1) * 64;
    const int wc = (wave & 1) * 32;
    const int b = m0 >> 11, t0 = m0 & (TLEN - 1);

    const _Float16* Ab  = h   + ((size_t)(b * NB + n) * TLEN + t0) * MLP;
    const _Float16* W2n = W2T + (size_t)n * O2 * MLP;

    floatx4 accA[4][2] = {};
    floatx4 accG[4][2] = {};

    const int lrow = lane & 15;
    const int q16  = (lane >> 4) << 4;
    const int swz  = (lane & 7) << 4;

    for (int k0 = 0; k0 < MLP; k0 += 64) {
        #pragma unroll
        for (int i = 0; i < 4; ++i) {
            int g = tid + i * 512;
            int r = g >> 3, kb = g & 7;
            int sk = kb ^ (r & 7);
            GLOAD_LDS(Ab + (size_t)r * MLP + k0 + sk * 8, sA + g * 8);
        }
        {
            int g = tid, r = g >> 3;
            int sk = (g & 7) ^ (r & 7);
            int ra = n0 + r;        if (ra > OUTC - 1) ra = OUTC - 1;
            int rg = OUTC + n0 + r; if (rg > O2 - 1)   rg = O2 - 1;
            GLOAD_LDS(W2n + (size_t)ra * MLP + k0 + sk * 8, sBa + g * 8);
            GLOAD_LDS(W2n + (size_t)rg * MLP + k0 + sk * 8, sBg + g * 8);
        }
        __syncthreads();
        #pragma unroll
        for (int kk = 0; kk < 2; ++kk) {
            half8 af[4], ba[2], bg[2];
            const int koff = (kk << 6) | q16;
            #pragma unroll
            for (int m = 0; m < 4; ++m)
                af[m] = *(const half8*)((const char*)sA + (wm + m * 16 + lrow) * 128 + (koff ^ swz));
            #pragma unroll
            for (int nf = 0; nf < 2; ++nf) {
                ba[nf] = *(const half8*)((const char*)sBa + (wc + nf * 16 + lrow) * 128 + (koff ^ swz));
                bg[nf] = *(const half8*)((const char*)sBg + (wc + nf * 16 + lrow) * 128 + (koff ^ swz));
            }
            #pragma unroll
            for (int m = 0; m < 4; ++m)
                #pragma unroll
                for (int nf = 0; nf < 2; ++nf) {
                    accA[m][nf] = __builtin_amdgcn_mfma_f32_16x16x32_f16(af[m], ba[nf], accA[m][nf], 0, 0, 0);
                    accG[m][nf] = __builtin_amdgcn_mfma_f32_16x16x32_f16(af[m], bg[nf], accG[m][nf], 0, 0, 0);
                }
        }
        __syncthreads();
    }

    const int rq = (lane >> 4) * 4;
    const float* b2n = b2 + n * O2;
    #pragma unroll
    for (int nf = 0; nf < 2; ++nf) {
        int c = n0 + wc + nf * 16 + lrow;
        bool valid = c < OUTC;
        int cl = valid ? c : OUTC - 1;
        float biasA = b2n[cl];
        float biasG = b2n[OUTC + cl];
        int rem = cl % 258;
        float w = fw[n * BWID + (rem >> 1)];
        _Float16* mb = mws + ((size_t)((b * NB + n) * OUTC + cl)) * TLEN + t0;
        #pragma unroll
        for (int m = 0; m < 4; ++m) {
            int tb = wm + m * 16 + rq;
            half4 vals;
            #pragma unroll
            for (int r = 0; r < 4; ++r) {
                float a = accA[m][nf][r] + biasA;
                float g = accG[m][nf][r] + biasG;
                vals[r] = (_Float16)(a * w * fast_sigmoid(g));
            }
            if (valid) *(half4*)(mb + tb) = vals;
        }
    }
}

// ---------------- gather: vectorized, 8 t-values per thread ----------------
__global__ __launch_bounds__(256) void gather_masks(const _Float16* __restrict__ mws,
                                                    float* __restrict__ out)
{
    const int f  = blockIdx.x;
    const int bc = blockIdx.y;
    const int b  = bc >> 1, cc = bc & 1;
    int nlo = (f >= 129) ? ((f - 65) >> 6) : 0;
    int nhi = f >> 6; if (nhi > 14) nhi = 14;
    const int t0 = threadIdx.x * 8;

    float a[8] = {0,0,0,0,0,0,0,0};
    float g[8] = {0,0,0,0,0,0,0,0};
    for (int nn = nlo; nn <= nhi; ++nn) {
        int bw = f - (nn << 6);
        int cbase = cc * 258 + (bw << 1);
        const _Float16* p = mws + ((size_t)((b * NB + nn) * OUTC + cbase)) * TLEN + t0;
        half8 va = *(const half8*)p;
        half8 vg = *(const half8*)(p + TLEN);
        #pragma unroll
        for (int j = 0; j < 8; ++j) { a[j] += (float)va[j]; g[j] += (float)vg[j]; }
    }
    float* ob = out + (((size_t)bc * NFREQ + f) * TLEN + t0) * REIM;
    #pragma unroll
    for (int j = 0; j < 4; ++j) {
        float4 v = make_float4(a[2*j], g[2*j], a[2*j+1], g[2*j+1]);
        *(float4*)(ob + j * 4) = v;
    }
}

extern "C" void kernel_launch(void* const* d_in, const int* in_sizes, int n_in,
                              void* d_out, int out_size, void* d_ws, size_t ws_size,
                              hipStream_t stream) {
    const float* q     = (const float*)d_in[0];
    const float* gamma = (const float*)d_in[1];
    const float* beta  = (const float*)d_in[2];
    const float* W1    = (const float*)d_in[3];
    const float* b1    = (const float*)d_in[4];
    const float* W2    = (const float*)d_in[5];
    const float* b2    = (const float*)d_in[6];
    const float* fw    = (const float*)d_in[7];

    _Float16* hws  = (_Float16*)d_ws;
    _Float16* mws  = hws + (size_t)RTOT * MLP;
    _Float16* qnws = mws + (size_t)BATCH * NB * OUTC * TLEN;
    _Float16* W1T  = qnws + (size_t)RTOT * EMB;
    _Float16* W2T  = W1T + (size_t)NB * EMB * MLP;

    ln_kernel<<<RTOT / 8, 256, 0, stream>>>(q, gamma, beta, qnws);
    transpose_cvt_all<<<240 + 136 * NB, 256, 0, stream>>>(W1, W2, W1T, W2T);
    gemm1_mfma<<<4 * 32 * NB, 512, 0, stream>>>(qnws, W1T, b1, hws);
    gemm2_mfma<<<9 * 16 * NB, 512, 0, stream>>>(hws, W2T, b2, fw, mws);
    gather_masks<<<dim3(NFREQ, BATCH * CCH), 256, 0, stream>>>(mws, (float*)d_out);
}